// Round 6
// baseline (1309.830 us; speedup 1.0000x reference)
//
#include <hip/hip_runtime.h>
#include <hip/hip_bf16.h>

#define NN 3136
#define CC 512
#define BBATCH 8

typedef __attribute__((ext_vector_type(8))) short short8;
typedef __attribute__((ext_vector_type(4))) float f32x4;

static __device__ __forceinline__ unsigned int pkbf(float a, float b) {
    union { __hip_bfloat162 h; unsigned int u; } v;
    v.h = __float22bfloat162_rn(make_float2(a, b));
    return v.u;
}

// ---------------- norms: inv[t][b][n] = 1/max(||f_t[b,:,n]||, 1e-12) ----------------
__global__ void norms_k(const float* __restrict__ f1, const float* __restrict__ f2,
                        const float* __restrict__ f3, float* __restrict__ inv) {
    int g = blockIdx.x * 256 + threadIdx.x;          // < 3*8*3136 = 75264
    int t = g / (BBATCH * NN);
    int r = g - t * (BBATCH * NN);
    int b = r / NN;
    int n = r - b * NN;
    const float* f = (t == 0) ? f1 : (t == 1) ? f2 : f3;
    const float* p = f + (size_t)b * CC * NN + n;
    float ss = 0.f;
#pragma unroll 8
    for (int c = 0; c < CC; ++c) { float x = p[(size_t)c * NN]; ss = fmaf(x, x, ss); }
    inv[g] = 1.0f / fmaxf(sqrtf(ss), 1e-12f);
}

// ---------------- init: out = fm1 ----------------
__global__ void init_k(const float4* __restrict__ src, float4* __restrict__ dst) {
    int g = blockIdx.x * 256 + threadIdx.x;
    dst[g] = src[g];
}

// ---------------- fused attention branch, out += 0.001 * (fk @ softmax(-q^k^)^T) ----------------
// Scores bounded in [-1,1] -> no running max. KT ([m][c], scaled, swizzled) and
// V ([c][m], raw) both double-buffered; V staged via m-major float4 loads so all
// LDS writes are vectorized. PV waves own (8 c-tiles x n-pair) to share A-frags.
static constexpr int KTOFF = 16384;   // ushorts per KT buffer (32 x 512)
static constexpr int VBASE = 32768;
static constexpr int VOFF  = 20480;   // ushorts per V buffer (512 x 40)
static constexpr int PBASE = VBASE + 2 * VOFF;   // 73728
static constexpr int VSTR  = 40;      // V row stride (80B, 16B-aligned rows)

__launch_bounds__(512, 2)
__global__ void attn_fused_k(const float* __restrict__ fq_all,
                             const float* __restrict__ f2_all,
                             const float* __restrict__ f3_all,
                             const float* __restrict__ invws,
                             float* __restrict__ out) {
    __shared__ __align__(16) unsigned short smem[PBASE + 64 * VSTR];  // 152576 B
    __shared__ float denbuf[8][16];

    unsigned short* pp = smem + PBASE;               // [64][VSTR]
    unsigned short* qstage = smem;                   // aliases KT bufs (pre-loop only)

    const int tid = threadIdx.x;
    const int w = tid >> 6, l = tid & 63;
    const int u = blockIdx.x;
    const int batch = u & 7;                          // 8 batches -> 8 XCDs
    const int unit = u >> 3;                          // 0..97
    const int br = unit & 1;
    const int qt = unit >> 1;                         // 0..48
    const int n0 = qt * 64;

    const float* fq = fq_all + (size_t)batch * CC * NN;
    const float* fk = (br ? f3_all : f2_all) + (size_t)batch * CC * NN;
    const float* inv1 = invws + batch * NN;
    const float* invk = invws + (1 + br) * (BBATCH * NN) + batch * NN;

    // ---- Q stage: [n][c] bf16, value = -f1*inv1 (sign folded), XOR-swizzled rows
    {
        int n = tid & 63, grp = tid >> 6;             // grp 0..7
        float s = -inv1[n0 + n];
        const float* src = fq + n0 + n;
        int sw = (n & 7) << 3;
#pragma unroll 4
        for (int ssi = 0; ssi < 16; ++ssi) {
            int cb = grp * 4 + 32 * ssi;
            float x0 = src[(size_t)(cb + 0) * NN], x1 = src[(size_t)(cb + 1) * NN];
            float x2 = src[(size_t)(cb + 2) * NN], x3 = src[(size_t)(cb + 3) * NN];
            uint2 y = { pkbf(x0 * s, x1 * s), pkbf(x2 * s, x3 * s) };
            *(uint2*)&qstage[n * 512 + (cb ^ sw)] = y;
        }
    }
    __syncthreads();

    // ---- Q fragments to registers: wave w owns n-cols 16*(w&3)..+15, all 16 k-steps
    short8 qf[16];
    {
        int nQ = 16 * (w & 3) + (l & 15);
        int sw = (nQ & 7) << 3;
#pragma unroll
        for (int ks = 0; ks < 16; ++ks)
            qf[ks] = *(const short8*)&qstage[nQ * 512 + ((ks * 32 + ((l >> 4) << 3)) ^ sw)];
    }
    __syncthreads();

    // ---- staging: KT [m][c] (scaled, swizzled; c-strided dwords) + V [c][m] (raw; m-major float4)
    auto stage = [&](int it, int bb2) {
        int m0 = it * 32;
        unsigned short* KT = smem + (bb2 ? KTOFF : 0);
        unsigned short* V  = smem + VBASE + (bb2 ? VOFF : 0);
        {   // KT path
            int m = tid & 31, grp = tid >> 5;         // grp 0..15
            float sk = invk[m0 + m];
            const float* src = fk + m0 + m;
            int swm = (m & 7) << 3;
            float xb[32];
#pragma unroll
            for (int ssi = 0; ssi < 8; ++ssi) {
                int cb = grp * 4 + 64 * ssi;
                xb[ssi * 4 + 0] = src[(size_t)(cb + 0) * NN];
                xb[ssi * 4 + 1] = src[(size_t)(cb + 1) * NN];
                xb[ssi * 4 + 2] = src[(size_t)(cb + 2) * NN];
                xb[ssi * 4 + 3] = src[(size_t)(cb + 3) * NN];
            }
#pragma unroll
            for (int ssi = 0; ssi < 8; ++ssi) {
                int cb = grp * 4 + 64 * ssi;
                uint2 y = { pkbf(xb[ssi*4+0] * sk, xb[ssi*4+1] * sk),
                            pkbf(xb[ssi*4+2] * sk, xb[ssi*4+3] * sk) };
                *(uint2*)&KT[m * 512 + (cb ^ swm)] = y;
            }
        }
        {   // V path: vectorized m-major
            int mq = (tid & 7) * 4, c0 = tid >> 3;    // c0 0..63
            const float* srcv = fk + m0 + mq;
#pragma unroll
            for (int ssi = 0; ssi < 8; ++ssi) {
                int c = c0 + 64 * ssi;
                float4 x = *(const float4*)&srcv[(size_t)c * NN];
                uint2 y = { pkbf(x.x, x.y), pkbf(x.z, x.w) };
                *(uint2*)&V[c * VSTR + mq] = y;
            }
        }
    };

    f32x4 acc[8][2];
#pragma unroll
    for (int ci = 0; ci < 8; ++ci) {
        acc[ci][0] = (f32x4){0.f, 0.f, 0.f, 0.f};
        acc[ci][1] = (f32x4){0.f, 0.f, 0.f, 0.f};
    }
    float den_part = 0.f;

    stage(0, 0);

    const int mt = w >> 2, nt = w & 3;                // score-phase wave layout
    const int np = w & 1, cg = w >> 1;                // PV-phase wave layout
    const int g = l >> 4, li = l & 15;
    const int mA = 16 * mt + li;                      // score A-row (m)
    const int swA = (mA & 7) << 3;
    const int nP = 16 * nt + li;                      // n index for P / den

    for (int it = 0; it < 98; ++it) {
        int bb2 = it & 1;
        __syncthreads();                              // buf[bb2] staged; P free

        // scores: D[m][n] = sum_c KT[m,c] * Qneg[c,n]
        f32x4 sacc = (f32x4){0.f, 0.f, 0.f, 0.f};
        const unsigned short* KT = smem + (bb2 ? KTOFF : 0);
#pragma unroll
        for (int ks = 0; ks < 16; ++ks) {
            short8 af = *(const short8*)&KT[mA * 512 + ((ks * 32 + (g << 3)) ^ swA)];
            sacc = __builtin_amdgcn_mfma_f32_16x16x32_bf16(af, qf[ks], sacc, 0, 0, 0);
        }
        // p = exp(s); s in [-1,1] so no max-subtraction needed
        float p0 = __expf(sacc[0]), p1 = __expf(sacc[1]);
        float p2 = __expf(sacc[2]), p3 = __expf(sacc[3]);
        den_part += (p0 + p1) + (p2 + p3);
        uint2 pw = { pkbf(p0, p1), pkbf(p2, p3) };
        *(uint2*)&pp[nP * VSTR + 16 * mt + 4 * g] = pw;   // P[n][m]

        if (it != 97) stage(it + 1, bb2 ^ 1);
        __syncthreads();                              // P visible; stage writes done

        // PV: O^T[c][n] += sum_m V[c,m] * P^T[m,n]; wave owns 8 c-tiles x n-pair
        const unsigned short* V = smem + VBASE + (bb2 ? VOFF : 0);
        short8 bf0 = *(const short8*)&pp[(16 * (2 * np + 0) + li) * VSTR + (g << 3)];
        short8 bf1 = *(const short8*)&pp[(16 * (2 * np + 1) + li) * VSTR + (g << 3)];
#pragma unroll
        for (int ci = 0; ci < 8; ++ci) {
            int cR = 16 * (8 * cg + ci) + li;
            short8 af = *(const short8*)&V[cR * VSTR + (g << 3)];
            acc[ci][0] = __builtin_amdgcn_mfma_f32_16x16x32_bf16(af, bf0, acc[ci][0], 0, 0, 0);
            acc[ci][1] = __builtin_amdgcn_mfma_f32_16x16x32_bf16(af, bf1, acc[ci][1], 0, 0, 0);
        }
    }

    // ---- den reduction (score-wave layout), then epilogue in PV layout
    den_part += __shfl_xor(den_part, 16);
    den_part += __shfl_xor(den_part, 32);
    if (l < 16) denbuf[w][l] = den_part;
    __syncthreads();
    float sc0 = 0.001f / (denbuf[2 * np + 0][li] + denbuf[4 + 2 * np + 0][li]);
    float sc1 = 0.001f / (denbuf[2 * np + 1][li] + denbuf[4 + 2 * np + 1][li]);

    float* op = out + (size_t)batch * CC * NN + n0;
    const int ncol0 = 16 * (2 * np + 0) + li;
    const int ncol1 = 16 * (2 * np + 1) + li;
#pragma unroll
    for (int ci = 0; ci < 8; ++ci) {
        int cbase = 16 * (8 * cg + ci) + 4 * g;
#pragma unroll
        for (int r = 0; r < 4; ++r) {
            atomicAdd(&op[(size_t)(cbase + r) * NN + ncol0], acc[ci][0][r] * sc0);
            atomicAdd(&op[(size_t)(cbase + r) * NN + ncol1], acc[ci][1][r] * sc1);
        }
    }
}

extern "C" void kernel_launch(void* const* d_in, const int* in_sizes, int n_in,
                              void* d_out, int out_size, void* d_ws, size_t ws_size,
                              hipStream_t stream) {
    (void)in_sizes; (void)n_in; (void)out_size; (void)ws_size;
    const float* f1 = (const float*)d_in[0];
    const float* f2 = (const float*)d_in[1];
    const float* f3 = (const float*)d_in[2];
    float* out = (float*)d_out;
    float* inv = (float*)d_ws;                        // 3*8*3136 floats = 301 KB

    norms_k<<<294, 256, 0, stream>>>(f1, f2, f3, inv);
    init_k<<<12544, 256, 0, stream>>>((const float4*)f1, (float4*)out);
    attn_fused_k<<<784, 512, 0, stream>>>(f1, f2, f3, inv, out);
}

// Round 7
// 1174.382 us; speedup vs baseline: 1.1153x; 1.1153x over previous
//
#include <hip/hip_runtime.h>
#include <hip/hip_bf16.h>

#define NN 3136
#define CC 512
#define BBATCH 8

typedef __attribute__((ext_vector_type(8))) short short8;
typedef __attribute__((ext_vector_type(4))) float f32x4;

static __device__ __forceinline__ unsigned int pkbf(float a, float b) {
    union { __hip_bfloat162 h; unsigned int u; } v;
    v.h = __float22bfloat162_rn(make_float2(a, b));
    return v.u;
}
static __device__ __forceinline__ unsigned short sbf(float a) {
    union { __hip_bfloat16 h; unsigned short u; } v;
    v.h = __float2bfloat16(a);
    return v.u;
}

// ---------------- norms: inv[t][b][n] = 1/max(||f_t[b,:,n]||, 1e-12) ----------------
__global__ void norms_k(const float* __restrict__ f1, const float* __restrict__ f2,
                        const float* __restrict__ f3, float* __restrict__ inv) {
    int g = blockIdx.x * 256 + threadIdx.x;          // < 3*8*3136 = 75264
    int t = g / (BBATCH * NN);
    int r = g - t * (BBATCH * NN);
    int b = r / NN;
    int n = r - b * NN;
    const float* f = (t == 0) ? f1 : (t == 1) ? f2 : f3;
    const float* p = f + (size_t)b * CC * NN + n;
    float ss = 0.f;
#pragma unroll 8
    for (int c = 0; c < CC; ++c) { float x = p[(size_t)c * NN]; ss = fmaf(x, x, ss); }
    inv[g] = 1.0f / fmaxf(sqrtf(ss), 1e-12f);
}

// ---------------- init: out = fm1 ----------------
__global__ void init_k(const float4* __restrict__ src, float4* __restrict__ dst) {
    int g = blockIdx.x * 256 + threadIdx.x;
    dst[g] = src[g];
}

// ---------------- fused attention branch, out += 0.001 * (fk @ softmax(-q^k^)^T) ----------------
// Scores bounded in [-1,1] -> no running max. KT ([m][c], scaled, swizzled) and
// V ([c][m], raw) double-buffered. T14 async-stage: global loads for tile it+1
// issued at iteration top (held in 32 VGPRs), LDS writes at iteration bottom,
// so L2 latency hides under the full iteration's compute. 2 barriers/iter.
static constexpr int KTOFF = 16384;   // ushorts per KT buffer (32 x 512)
static constexpr int VBASE = 32768;
static constexpr int VOFF  = 20480;   // ushorts per V buffer (512 x 40)
static constexpr int PBASE = VBASE + 2 * VOFF;   // 73728
static constexpr int VSTR  = 40;

__launch_bounds__(512, 2)
__global__ void attn_fused_k(const float* __restrict__ fq_all,
                             const float* __restrict__ f2_all,
                             const float* __restrict__ f3_all,
                             const float* __restrict__ invws,
                             float* __restrict__ out) {
    __shared__ __align__(16) unsigned short smem[PBASE + 64 * VSTR];  // 152576 B
    __shared__ float denbuf[8][16];

    unsigned short* pp = smem + PBASE;               // [64][VSTR]
    unsigned short* qstage = smem;                   // aliases KT bufs (pre-loop only)

    const int tid = threadIdx.x;
    const int w = tid >> 6, l = tid & 63;
    const int u = blockIdx.x;
    const int batch = u & 7;                          // 8 batches -> 8 XCDs
    const int unit = u >> 3;                          // 0..97
    const int br = unit & 1;
    const int qt = unit >> 1;                         // 0..48
    const int n0 = qt * 64;

    const float* fq = fq_all + (size_t)batch * CC * NN;
    const float* fk = (br ? f3_all : f2_all) + (size_t)batch * CC * NN;
    const float* inv1 = invws + batch * NN;
    const float* invk = invws + (1 + br) * (BBATCH * NN) + batch * NN;

    // ---- Q stage: [n][c] bf16, value = -f1*inv1 (sign folded), XOR-swizzled rows
    {
        int n = tid & 63, grp = tid >> 6;             // grp 0..7
        float s = -inv1[n0 + n];
        const float* src = fq + n0 + n;
        int sw = (n & 7) << 3;
#pragma unroll 4
        for (int ssi = 0; ssi < 16; ++ssi) {
            int cb = grp * 4 + 32 * ssi;
            int b0 = cb * NN;
            float x0 = src[b0], x1 = src[b0 + NN];
            float x2 = src[b0 + 2 * NN], x3 = src[b0 + 3 * NN];
            uint2 y = { pkbf(x0 * s, x1 * s), pkbf(x2 * s, x3 * s) };
            *(uint2*)&qstage[n * 512 + (cb ^ sw)] = y;
        }
    }
    __syncthreads();

    // ---- Q fragments to registers: wave w owns n-cols 16*(w&3)..+15, all 16 k-steps
    short8 qf[16];
    {
        int nQ = 16 * (w & 3) + (l & 15);
        int sw = (nQ & 7) << 3;
#pragma unroll
        for (int ks = 0; ks < 16; ++ks)
            qf[ks] = *(const short8*)&qstage[nQ * 512 + ((ks * 32 + ((l >> 4) << 3)) ^ sw)];
    }
    __syncthreads();

    const int mstg = tid & 31, gstg = tid >> 5;       // staging decomposition
    const int swm = (mstg & 7) << 3;

    // issue the 32 global loads for tile `it` into xb (int 32-bit offsets)
    auto stage_load = [&](int it, float* xb) {
        const float* src = fk + it * 32 + mstg;
#pragma unroll
        for (int ssi = 0; ssi < 8; ++ssi) {
            int b0 = (gstg * 4 + 64 * ssi) * NN;
            xb[ssi * 4 + 0] = src[b0];
            xb[ssi * 4 + 1] = src[b0 + NN];
            xb[ssi * 4 + 2] = src[b0 + 2 * NN];
            xb[ssi * 4 + 3] = src[b0 + 3 * NN];
        }
    };
    // convert + write KT (scaled, swizzled) and V (raw) for tile `it` into buf bb
    auto stage_write = [&](int it, const float* xb, int bb) {
        float sk = invk[it * 32 + mstg];
        unsigned short* KT = smem + (bb ? KTOFF : 0);
        unsigned short* V  = smem + VBASE + (bb ? VOFF : 0);
#pragma unroll
        for (int ssi = 0; ssi < 8; ++ssi) {
            int cb = gstg * 4 + 64 * ssi;
            float x0 = xb[ssi*4+0], x1 = xb[ssi*4+1], x2 = xb[ssi*4+2], x3 = xb[ssi*4+3];
            uint2 y = { pkbf(x0 * sk, x1 * sk), pkbf(x2 * sk, x3 * sk) };
            *(uint2*)&KT[mstg * 512 + (cb ^ swm)] = y;
            unsigned short* vb = &V[cb * VSTR + mstg];
            vb[0]        = sbf(x0);
            vb[VSTR]     = sbf(x1);
            vb[2 * VSTR] = sbf(x2);
            vb[3 * VSTR] = sbf(x3);
        }
    };

    f32x4 acc[8][2];
#pragma unroll
    for (int ci = 0; ci < 8; ++ci) {
        acc[ci][0] = (f32x4){0.f, 0.f, 0.f, 0.f};
        acc[ci][1] = (f32x4){0.f, 0.f, 0.f, 0.f};
    }
    float den_part = 0.f;
    float xb[32];

    stage_load(0, xb);
    stage_write(0, xb, 0);

    const int mt = w >> 2, nt = w & 3;                // score-phase wave layout
    const int np = w & 1, cg = w >> 1;                // PV-phase wave layout
    const int g = l >> 4, li = l & 15;
    const int mA = 16 * mt + li;                      // score A-row (m)
    const int swA = (mA & 7) << 3;
    const int nP = 16 * nt + li;                      // n index for P / den

    for (int it = 0; it < 98; ++it) {
        int cur = it & 1;
        __syncthreads();                              // b1: buf[cur] staged; P free

        if (it < 97) stage_load(it + 1, xb);          // async issue, consumed at bottom

        // scores: D[m][n] = sum_c KT[m,c] * Qneg[c,n]
        f32x4 sacc = (f32x4){0.f, 0.f, 0.f, 0.f};
        const unsigned short* KT = smem + (cur ? KTOFF : 0);
#pragma unroll
        for (int ks = 0; ks < 16; ++ks) {
            short8 af = *(const short8*)&KT[mA * 512 + ((ks * 32 + (g << 3)) ^ swA)];
            sacc = __builtin_amdgcn_mfma_f32_16x16x32_bf16(af, qf[ks], sacc, 0, 0, 0);
        }
        // p = exp(s); s in [-1,1] so no max-subtraction needed
        float p0 = __expf(sacc[0]), p1 = __expf(sacc[1]);
        float p2 = __expf(sacc[2]), p3 = __expf(sacc[3]);
        den_part += (p0 + p1) + (p2 + p3);
        uint2 pw = { pkbf(p0, p1), pkbf(p2, p3) };
        *(uint2*)&pp[nP * VSTR + 16 * mt + 4 * g] = pw;   // P[n][m]

        __syncthreads();                              // b2: P visible

        // PV: O^T[c][n] += sum_m V[c,m] * P^T[m,n]; wave owns 8 c-tiles x n-pair
        const unsigned short* V = smem + VBASE + (cur ? VOFF : 0);
        short8 bf0 = *(const short8*)&pp[(32 * np + li) * VSTR + (g << 3)];
        short8 bf1 = *(const short8*)&pp[(32 * np + 16 + li) * VSTR + (g << 3)];
        const unsigned short* vbase = &V[(128 * cg + li) * VSTR + (g << 3)];
#pragma unroll
        for (int ci = 0; ci < 8; ++ci) {
            short8 af = *(const short8*)&vbase[ci * 16 * VSTR];
            acc[ci][0] = __builtin_amdgcn_mfma_f32_16x16x32_bf16(af, bf0, acc[ci][0], 0, 0, 0);
            acc[ci][1] = __builtin_amdgcn_mfma_f32_16x16x32_bf16(af, bf1, acc[ci][1], 0, 0, 0);
        }

        if (it < 97) stage_write(it + 1, xb, cur ^ 1);  // writes drain at next b1
    }

    // ---- den reduction (score-wave layout), then epilogue in PV layout
    den_part += __shfl_xor(den_part, 16);
    den_part += __shfl_xor(den_part, 32);
    if (l < 16) denbuf[w][l] = den_part;
    __syncthreads();
    float sc0 = 0.001f / (denbuf[2 * np + 0][li] + denbuf[4 + 2 * np + 0][li]);
    float sc1 = 0.001f / (denbuf[2 * np + 1][li] + denbuf[4 + 2 * np + 1][li]);

    float* op = out + (size_t)batch * CC * NN + n0;
    const int ncol0 = 16 * (2 * np + 0) + li;
    const int ncol1 = 16 * (2 * np + 1) + li;
#pragma unroll
    for (int ci = 0; ci < 8; ++ci) {
        int cbase = 16 * (8 * cg + ci) + 4 * g;
#pragma unroll
        for (int r = 0; r < 4; ++r) {
            atomicAdd(&op[(size_t)(cbase + r) * NN + ncol0], acc[ci][0][r] * sc0);
            atomicAdd(&op[(size_t)(cbase + r) * NN + ncol1], acc[ci][1][r] * sc1);
        }
    }
}

extern "C" void kernel_launch(void* const* d_in, const int* in_sizes, int n_in,
                              void* d_out, int out_size, void* d_ws, size_t ws_size,
                              hipStream_t stream) {
    (void)in_sizes; (void)n_in; (void)out_size; (void)ws_size;
    const float* f1 = (const float*)d_in[0];
    const float* f2 = (const float*)d_in[1];
    const float* f3 = (const float*)d_in[2];
    float* out = (float*)d_out;
    float* inv = (float*)d_ws;                        // 3*8*3136 floats = 301 KB

    norms_k<<<294, 256, 0, stream>>>(f1, f2, f3, inv);
    init_k<<<12544, 256, 0, stream>>>((const float4*)f1, (float4*)out);
    attn_fused_k<<<784, 512, 0, stream>>>(f1, f2, f3, inv, out);
}